// Round 12
// baseline (4449.942 us; speedup 1.0000x reference)
//
#include <hip/hip_runtime.h>
#include <cstdint>
#include <cstddef>

#define NN 128
#define LL 512
#define DD 512
#define HH 1024
#define NJ 4096            // packed gate cols, j = 4*hc + g
#define ASTR 1024          // A row stride (fp16 elems)
#define BSTR 1024          // B row stride (fp16 elems)
#define NCH 4              // K chunks of 256

typedef __attribute__((ext_vector_type(8))) _Float16 half8;
typedef __attribute__((ext_vector_type(4))) float f32x4;

__device__ __forceinline__ unsigned short f2h(float x) {
  union { _Float16 h; unsigned short u; } v; v.h = (_Float16)x; return v.u;
}
__device__ __forceinline__ float sigf(float x) { return 1.0f / (1.0f + __expf(-x)); }

__device__ __forceinline__ void glds16(const void* g, const void* l) {
  __builtin_amdgcn_global_load_lds(
      (const __attribute__((address_space(1))) unsigned int*)g,
      (__attribute__((address_space(3))) unsigned int*)l, 16, 0, 0);
}

// ---------------- sT[l*NN + n] = sum_d X[n,l,d] ----------------
__global__ __launch_bounds__(256)
void sum_rows_kernel(const float* __restrict__ X, float* __restrict__ sT) {
  int row  = blockIdx.x * 4 + (threadIdx.x >> 6);
  int lane = threadIdx.x & 63;
  const float* x = X + (size_t)row * DD + lane * 8;
  float4 a = *(const float4*)x;
  float4 b = *(const float4*)(x + 4);
  float v = (a.x + a.y) + (a.z + a.w) + (b.x + b.y) + (b.z + b.w);
#pragma unroll
  for (int off = 32; off > 0; off >>= 1) v += __shfl_down(v, off, 64);
  if (lane == 0) {
    int n = row >> 9, l = row & 511;
    sT[l * NN + n] = v;
  }
}

// ---------------- pack W into fp16, gate-interleaved rows ----------------
__global__ __launch_bounds__(256)
void wpack_kernel(const float* __restrict__ Wi, const float* __restrict__ Wf,
                  const float* __restrict__ Wg, const float* __restrict__ Wo,
                  unsigned short* __restrict__ B) {
  int idx = blockIdx.x * 256 + threadIdx.x;    // NJ*128 threads
  int j = idx >> 7;
  int k = (idx & 127) << 3;
  int hc = j >> 2, g = j & 3;
  const float* W = (g == 0) ? Wi : (g == 1) ? Wf : (g == 2) ? Wg : Wo;
  const float4 x0 = *(const float4*)(W + (size_t)hc * HH + k);
  const float4 x1 = *(const float4*)(W + (size_t)hc * HH + k + 4);
  float xv[8] = {x0.x, x0.y, x0.z, x0.w, x1.x, x1.y, x1.z, x1.w};
  unsigned short* d = B + (size_t)j * BSTR + k;
#pragma unroll
  for (int e = 0; e < 8; ++e) d[e] = f2h(xv[e]);
}

// ---------------- pack lambda / (binv+b) gate-interleaved ----------------
__global__ __launch_bounds__(256)
void pack_kernel(const float* li, const float* lf, const float* lg, const float* lo_,
                 const float* bvi, const float* bvf, const float* bvg, const float* bvo,
                 const float* bi, const float* bf_, const float* bg, const float* bo,
                 float* __restrict__ lamP, float* __restrict__ biasP) {
  int j = blockIdx.x * 256 + threadIdx.x;
  int hc = j >> 2, g = j & 3;
  const float* lam = (g == 0) ? li : (g == 1) ? lf : (g == 2) ? lg : lo_;
  const float* bv  = (g == 0) ? bvi : (g == 1) ? bvf : (g == 2) ? bvg : bvo;
  const float* bb  = (g == 0) ? bi : (g == 1) ? bf_ : (g == 2) ? bg : bo;
  lamP[j] = lam[hc];
  biasP[j] = bv[hc] + bb[hc];
}

// ---------------- t = 0 (h=0, c=0: no GEMM) ----------------
__global__ __launch_bounds__(256)
void t0_kernel(const float* __restrict__ sT, const float* __restrict__ lamP,
               const float* __restrict__ biasP, float* __restrict__ out,
               float* __restrict__ cbuf, unsigned short* __restrict__ A0) {
  int id = blockIdx.x * 256 + threadIdx.x;   // NN*HH threads
  int n = id >> 10, hc = id & 1023;
  float sv = sT[n];                          // t = 0 slice
  float4 lam = *(const float4*)(lamP + 4 * hc);
  float4 bia = *(const float4*)(biasP + 4 * hc);
  float vi = sigf(sv * lam.x + bia.x);
  float vg = sigf(sv * lam.z + bia.z);
  float vo = sigf(sv * lam.w + bia.w);
  float cn = vi * vg;
  float hn = vo * sigf(cn);
  cbuf[n * HH + hc] = cn;
  out[(size_t)n * (LL * HH) + hc] = hn;
  A0[(size_t)n * ASTR + hc] = f2h(hn);
}

// ---------------- one LSTM step: fp16 GEMM, B in registers ----------------
// grid 512 blocks (XCD-swizzled, 2 blocks/CU), block 128 thr = 2 waves.
// block tile 32m x 32j x K1024; wave tile 32m x 16j (identical to R11 wave).
// A (shared by both waves) via LDS double-buffer [2][2sub][32][128] fp16 with
// proven XOR swizzle; B (private per wave) loaded global->VGPR directly
// (L2-resident, natural fragment layout, no swizzle). 2 independent blocks
// per CU overlap each other's vmcnt/barrier stalls.
// Issue order per chunk (pinned by sched_barrier): A-glds x8, B-dwordx4 x8.
// Wait vmcnt(16) => chunk c's A+B retired while c+1 stays in flight.
__global__ __launch_bounds__(128, 2)
void step_kernel(const unsigned short* __restrict__ Aprev,
                 const unsigned short* __restrict__ Bbuf,
                 const float* __restrict__ sT, const float* __restrict__ lamP,
                 const float* __restrict__ biasP, float* __restrict__ out,
                 float* __restrict__ cbuf, unsigned short* __restrict__ Acur, int t)
{
  __shared__ alignas(16) short lds[2][8192];   // A only: 16 KB x 2

  const int tid = threadIdx.x;
  const int ln  = tid & 63;
  const int w   = tid >> 6;          // wave 0..1

  // XCD-contiguous mapping: XCD x owns wl in [64x, 64x+64)
  const int bid = blockIdx.x;
  const int wl  = (bid & 7) * 64 + (bid >> 3);
  const int Nt  = wl >> 2;           // 0..127 (j tile)
  const int Mt  = wl & 3;            // 0..3   (m tile)
  const int n0  = Mt * 32;
  const int j0  = Nt * 32;

  const int ps = ln & 15;
  const int rr = ln >> 4;
  const int hs8 = (ln >> 4) * 8;

  // --- A staging pieces: 16 x 1KB per chunk; wave w owns [8w, 8w+8) ---
  const char* srcb[8];
  int ldsoff[8];
#pragma unroll
  for (int i = 0; i < 8; ++i) {
    int p = w * 8 + i;               // 0..15
    int sub = p >> 3;                // wave0 -> sub0, wave1 -> sub1
    int pr  = p & 7;
    int r   = pr * 4 + rr;           // 0..31
    int sp  = (ps & 8) | ((ps ^ r) & 7);
    srcb[i] = (const char*)(Aprev + (size_t)(n0 + r) * ASTR + sub * 128 + sp * 8);
    ldsoff[i] = sub * 4096 + pr * 512;
  }

  // --- A fragment read offsets (proven swizzle, per 128-col sub-plane) ---
  int aoff[2][8];
#pragma unroll
  for (int sl = 0; sl < 8; ++sl) {
    int sub = sl >> 2;
    int s   = (sl & 3) * 4 + (ln >> 4);
#pragma unroll
    for (int mf = 0; mf < 2; ++mf) {
      int rA = mf * 16 + (ln & 15);
      aoff[mf][sl] = sub * 4096 + rA * 128 + (((s & 8) | ((s ^ rA) & 7)) << 3);
    }
  }

  // --- B source: this lane's row, natural layout ---
  const unsigned short* Bp = Bbuf + (size_t)(j0 + w * 16 + (ln & 15)) * BSTR;

  // --- epilogue constants + prefetch ---
  const int jj = j0 + w * 16 + (ln & 15);
  const float lamv = lamP[jj];
  const float biav = biasP[jj];
  const int rbase = (ln >> 4) * 4;
  const int hc = jj >> 2;
  float cold[2][4], svp[2][4];
#pragma unroll
  for (int mf = 0; mf < 2; ++mf)
#pragma unroll
    for (int r = 0; r < 4; ++r) {
      const int m = n0 + mf * 16 + rbase + r;
      cold[mf][r] = cbuf[m * HH + hc];
      svp[mf][r]  = sT[t * NN + m];
    }

  f32x4 acc0 = {0.f,0.f,0.f,0.f};
  f32x4 acc1 = {0.f,0.f,0.f,0.f};
  half8 brA[8], brB[8];              // B double-buffer (static indexing only)

  stageA0: ;
  // prologue: A(0), B(0)
#pragma unroll
  for (int i = 0; i < 8; ++i) glds16(srcb[i], &lds[0][ldsoff[i]]);
  __builtin_amdgcn_sched_barrier(0);
#pragma unroll
  for (int sl = 0; sl < 8; ++sl)
    brA[sl] = *(const half8*)(Bp + sl * 32 + hs8);
  __builtin_amdgcn_sched_barrier(0);

#pragma unroll
  for (int c = 0; c < NCH; ++c) {
    const int b = c & 1;
    __builtin_amdgcn_s_barrier();               // buf b free (prev compute done)
    if (c < NCH - 1) {
      const int co = (c + 1) * 512;             // bytes per A row
#pragma unroll
      for (int i = 0; i < 8; ++i) glds16(srcb[i] + co, &lds[b ^ 1][ldsoff[i]]);
      __builtin_amdgcn_sched_barrier(0);
      const int ce = (c + 1) * 256;             // elements per B row
      if (b) {
#pragma unroll
        for (int sl = 0; sl < 8; ++sl) brA[sl] = *(const half8*)(Bp + ce + sl * 32 + hs8);
      } else {
#pragma unroll
        for (int sl = 0; sl < 8; ++sl) brB[sl] = *(const half8*)(Bp + ce + sl * 32 + hs8);
      }
      __builtin_amdgcn_sched_barrier(0);
      asm volatile("s_waitcnt vmcnt(16)" ::: "memory");  // A(c)+B(c) retired
    } else {
      asm volatile("s_waitcnt vmcnt(0)" ::: "memory");
    }
    __builtin_amdgcn_sched_barrier(0);
    __builtin_amdgcn_s_barrier();               // chunk c visible block-wide
#pragma unroll
    for (int sl = 0; sl < 8; ++sl) {
      half8 a0 = *(const half8*)&lds[b][aoff[0][sl]];
      half8 a1 = *(const half8*)&lds[b][aoff[1][sl]];
      half8 bb = b ? brB[sl] : brA[sl];
      acc0 = __builtin_amdgcn_mfma_f32_16x16x32_f16(a0, bb, acc0, 0, 0, 0);
      acc1 = __builtin_amdgcn_mfma_f32_16x16x32_f16(a1, bb, acc1, 0, 0, 0);
    }
  }

  // ---- epilogue: fuse 4 gates (adjacent lanes) -> c,h ; emit h + h_fp16 ----
#pragma unroll
  for (int mf = 0; mf < 2; ++mf) {
    const int m0 = n0 + mf * 16 + rbase;
#pragma unroll
    for (int r = 0; r < 4; ++r) {
      const int m = m0 + r;
      float a = (mf == 0) ? acc0[r] : acc1[r];
      float v = sigf(a + svp[mf][r] * lamv + biav);
      const int base = ln & ~3;
      float vi = __shfl(v, base + 0, 64);
      float vf = __shfl(v, base + 1, 64);
      float vg = __shfl(v, base + 2, 64);
      float vo = __shfl(v, base + 3, 64);
      if ((ln & 3) == 0) {
        float cn = vf * cold[mf][r] + vi * vg;
        float hn = vo * sigf(cn);
        cbuf[m * HH + hc] = cn;
        out[(size_t)m * (LL * HH) + (size_t)t * HH + hc] = hn;
        Acur[(size_t)m * ASTR + hc] = f2h(hn);
      }
    }
  }
}

extern "C" void kernel_launch(void* const* d_in, const int* in_sizes, int n_in,
                              void* d_out, int out_size, void* d_ws, size_t ws_size,
                              hipStream_t stream) {
  const float* X    = (const float*)d_in[0];
  const float* lami = (const float*)d_in[1];
  const float* bvi  = (const float*)d_in[2];
  const float* Wi   = (const float*)d_in[3];
  const float* bi   = (const float*)d_in[4];
  const float* lamf = (const float*)d_in[5];
  const float* bvf  = (const float*)d_in[6];
  const float* Wf   = (const float*)d_in[7];
  const float* bf_  = (const float*)d_in[8];
  const float* lamg = (const float*)d_in[9];
  const float* bvg  = (const float*)d_in[10];
  const float* Wg   = (const float*)d_in[11];
  const float* bg   = (const float*)d_in[12];
  const float* lamo = (const float*)d_in[13];
  const float* bvo  = (const float*)d_in[14];
  const float* Wo   = (const float*)d_in[15];
  const float* bo   = (const float*)d_in[16];

  float* out  = (float*)d_out;

  // workspace layout (~9.7 MB)
  float* cbuf  = (float*)d_ws;                         // 128*1024 f32
  float* sT    = cbuf + (size_t)NN * HH;               // 512*128  f32
  float* lamP  = sT + (size_t)NN * LL;                 // 4096 f32
  float* biasP = lamP + NJ;                            // 4096 f32
  unsigned short* A0 = (unsigned short*)(biasP + NJ);  // 128*1024 fp16
  unsigned short* A1 = A0 + (size_t)NN * ASTR;         // 128*1024 fp16
  unsigned short* Bb = A1 + (size_t)NN * ASTR;         // 4096*1024 fp16 (8 MB)

  sum_rows_kernel<<<(NN * LL) / 4, 256, 0, stream>>>(X, sT);
  wpack_kernel<<<(NJ * 128) / 256, 256, 0, stream>>>(Wi, Wf, Wg, Wo, Bb);
  pack_kernel<<<NJ / 256, 256, 0, stream>>>(lami, lamf, lamg, lamo,
                                            bvi, bvf, bvg, bvo,
                                            bi, bf_, bg, bo, lamP, biasP);
  t0_kernel<<<(NN * HH) / 256, 256, 0, stream>>>(sT, lamP, biasP, out, cbuf, A0);

  for (int t = 1; t < LL; ++t) {
    const unsigned short* Ap = (t & 1) ? A0 : A1;
    unsigned short* Ac = (t & 1) ? (unsigned short*)A1 : A0;
    step_kernel<<<512, 128, 0, stream>>>(Ap, Bb, sT, lamP, biasP, out, cbuf, Ac, t);
  }
}